// Round 16
// baseline (361.457 us; speedup 1.0000x reference)
//
#include <hip/hip_runtime.h>
#include <hip/hip_bf16.h>
#include <hip/hip_cooperative_groups.h>

namespace cg = cooperative_groups;

// HoloAttention: out = (Re(cumsum_t(x@Wv^T * e^{i t f}) * e^{-i t f})) @ Wo^T
// (k-projection in reference is dead code — skipped.)
//
// R22: ENTIRE chain fused into ONE cooperative kernel with 4 grid.sync()s:
//   cast -> gemm1(+sums) -> pass2 -> pass3 -> gemm2.
// Rationale: tail (total - 2 gemms) is pinned at ~114us across 5 rounds but
// its kernels' BW roofline sums to ~30us — the ~80us residual is attributed
// to inter-kernel launch/serialization gaps (5 dependent dispatches x ~10us
// + ramp). Geometry is exact for co-residency: 256 blocks x 512 thr, 128KB
// LDS -> 1 block/CU x 256 CUs. gemm grid was already 256 (64x4 tiles);
// pass2 = 2048 waves = 256x8; pass3 = 512 (b,chunk) units = 256x2; cast =
// grid-stride (18 iters). GEMM K-loop body moved VERBATIM into a device fn
// (R8 structure, frozen: P3 vmcnt(8), 54-62us drift band).
// Aliasing ordered by grid syncs: ret reuses x_bf region (x_bf dead after
// gemm1); v (bf16) in d_out, dead before gemm2 overwrites d_out.

#define B_  2
#define T_  8192
#define D_  1024
#define BT_ 16384
#define CS_ 32
#define NCHUNK_ 256

typedef __attribute__((ext_vector_type(4))) float f32x4;
typedef __attribute__((ext_vector_type(8))) short bf16x8;
typedef __attribute__((ext_vector_type(8))) unsigned short ushort8;

static __device__ inline unsigned short f2bf(float f) {
    union { float f; unsigned int u; } a;
    a.f = f;
    unsigned int u = a.u;
    return (unsigned short)((u + 0x7FFFu + ((u >> 16) & 1u)) >> 16);  // RNE
}
static __device__ inline float bf2f(unsigned short h) {
    union { unsigned int u; float f; } a;
    a.u = ((unsigned int)h) << 16;
    return a.f;
}

// C[M,N] = A[M,K] (bf16 row-major) @ Bm[N,K]^T (bf16 row-major).
// 256x256 tile, BK=64, 512 threads = 8 waves. 16x16x32 MFMA, acc[8][4].
// LDS: 2 slots x (A 256x64 + B 256x64) bf16 = 131072 B (passed in).
// Stage map: P0: t+1 A1,A3 | P1: t+2 A0,A2 | P2: t+2 B0,B1 | P3: t+2 B2,B3.
// Steady-state wait: P3 vmcnt(8) ONLY (R8 structure — frozen).
template <bool BF16OUT, bool FUSE_SUMS>
__device__ __forceinline__ void gemm_body(const short* A, const short* Bm,
                                          void* Cout, const float* freqs,
                                          float* csum, int M, int N, int K,
                                          short* lds) {
    const int tid = threadIdx.x;
    const int lane = tid & 63;
    const int wave = tid >> 6;
    const int wm = wave >> 2, wn = wave & 3;

    const int nb = N >> 8;               // N-blocks (4)
    const int id = blockIdx.x;
    const int xcd = id & 7;
    const int slot = id >> 3;
    const int bn = (slot % nb) * 256;
    const int bm = (xcd * ((M >> 8) >> 3) + slot / nb) * 256;

    // --- staging: granule g = 64 rows of A (g=0..3) or B (g=4..7).
    const int srow = lane >> 3;
    const int sg = lane & 7;
    const size_t cstep = (size_t)64 * K;
    const short* gA = A + (size_t)(bm + wave * 8 + srow) * K + ((sg ^ srow) * 8);
    const short* gB = Bm + (size_t)(bn + wave * 8 + srow) * K + ((sg ^ srow) * 8);

    auto stage1 = [&](int kt, int g) {
        const int c = g & 3;
        const short* src = ((g & 4) ? gB : gA) + c * cstep + kt * 64;
        short* dst = &lds[(kt & 1) * 32768 + ((g & 4) ? 16384 : 0) + c * 4096 + wave * 512];
        __builtin_amdgcn_global_load_lds(
            (const __attribute__((address_space(1))) void*)src,
            (__attribute__((address_space(3))) void*)dst, 16, 0, 0);
    };

    // --- fragment read bases (shorts). m&7 == lane&7 for every fragment row.
    const int l15 = lane & 15;
    const int c4r = lane >> 4;
    const int swz0 = ((c4r) ^ (lane & 7)) * 8;
    const int swz1 = ((4 + c4r) ^ (lane & 7)) * 8;
    const int abase = (wm * 128 + l15) * 64;
    const int bbase = 16384 + (wn * 64 + l15) * 64;

    f32x4 acc[8][4] = {};

    // --- prologue: tile0 fully (8), tile1 all but A1,A3 (6).
    stage1(0, 0); stage1(0, 1); stage1(0, 2); stage1(0, 3);
    stage1(0, 4); stage1(0, 5); stage1(0, 6); stage1(0, 7);
    stage1(1, 0); stage1(1, 2);
    stage1(1, 4); stage1(1, 5); stage1(1, 6); stage1(1, 7);
    asm volatile("s_waitcnt vmcnt(6)" ::: "memory");   // ALL of tile0 landed
    __builtin_amdgcn_sched_barrier(0);
    __builtin_amdgcn_s_barrier();

    const int NT = K >> 6;  // 16
#pragma unroll 1
    for (int t = 0; t < NT; ++t) {
        const int sb = (t & 1) * 32768;
        const bool pf = (t + 2 < NT);
        bf16x8 av[4][2], b01[2][2], b23[2][2];

        // ===== P0: reads A frags 0-3 (8) + b01 (4); stage t+1 A1,A3
#pragma unroll
        for (int ii = 0; ii < 4; ++ii) {
            av[ii][0] = *(const bf16x8*)&lds[sb + abase + ii * 1024 + swz0];
            av[ii][1] = *(const bf16x8*)&lds[sb + abase + ii * 1024 + swz1];
        }
#pragma unroll
        for (int j = 0; j < 2; ++j) {
            b01[j][0] = *(const bf16x8*)&lds[sb + bbase + j * 1024 + swz0];
            b01[j][1] = *(const bf16x8*)&lds[sb + bbase + j * 1024 + swz1];
        }
        if (t + 1 < NT) { stage1(t + 1, 1); stage1(t + 1, 3); }
        __builtin_amdgcn_s_barrier();
        asm volatile("s_waitcnt lgkmcnt(0)" ::: "memory");
        __builtin_amdgcn_sched_barrier(0);
        __builtin_amdgcn_s_setprio(1);
#pragma unroll
        for (int ks = 0; ks < 2; ++ks)
#pragma unroll
            for (int ii = 0; ii < 4; ++ii)
#pragma unroll
                for (int j = 0; j < 2; ++j)
                    acc[ii][j] = __builtin_amdgcn_mfma_f32_16x16x32_bf16(
                        av[ii][ks], b01[j][ks], acc[ii][j], 0, 0, 0);
        __builtin_amdgcn_s_setprio(0);
        __builtin_amdgcn_s_barrier();

        // ===== P1: reads b23 (4); stage t+2 A0,A2
#pragma unroll
        for (int j = 0; j < 2; ++j) {
            b23[j][0] = *(const bf16x8*)&lds[sb + bbase + (2 + j) * 1024 + swz0];
            b23[j][1] = *(const bf16x8*)&lds[sb + bbase + (2 + j) * 1024 + swz1];
        }
        if (pf) { stage1(t + 2, 0); stage1(t + 2, 2); }
        __builtin_amdgcn_s_barrier();
        asm volatile("s_waitcnt lgkmcnt(0)" ::: "memory");
        __builtin_amdgcn_sched_barrier(0);
        __builtin_amdgcn_s_setprio(1);
#pragma unroll
        for (int ks = 0; ks < 2; ++ks)
#pragma unroll
            for (int ii = 0; ii < 4; ++ii)
#pragma unroll
                for (int j = 0; j < 2; ++j)
                    acc[ii][2 + j] = __builtin_amdgcn_mfma_f32_16x16x32_bf16(
                        av[ii][ks], b23[j][ks], acc[ii][2 + j], 0, 0, 0);
        __builtin_amdgcn_s_setprio(0);
        __builtin_amdgcn_s_barrier();

        // ===== P2: reads A frags 4-7 (8); stage t+2 B0,B1.
        //       A1,A3(t) staged at t-1 P0 (6 phases ago) — no explicit wait
        //       (R8 structure — frozen).
#pragma unroll
        for (int ii = 0; ii < 4; ++ii) {
            av[ii][0] = *(const bf16x8*)&lds[sb + abase + (4 + ii) * 1024 + swz0];
            av[ii][1] = *(const bf16x8*)&lds[sb + abase + (4 + ii) * 1024 + swz1];
        }
        if (pf) { stage1(t + 2, 4); stage1(t + 2, 5); }
        __builtin_amdgcn_s_barrier();
        asm volatile("s_waitcnt lgkmcnt(0)" ::: "memory");
        __builtin_amdgcn_sched_barrier(0);
        __builtin_amdgcn_s_setprio(1);
#pragma unroll
        for (int ks = 0; ks < 2; ++ks)
#pragma unroll
            for (int ii = 0; ii < 4; ++ii)
#pragma unroll
                for (int j = 0; j < 2; ++j)
                    acc[4 + ii][2 + j] = __builtin_amdgcn_mfma_f32_16x16x32_bf16(
                        av[ii][ks], b23[j][ks], acc[4 + ii][2 + j], 0, 0, 0);
        __builtin_amdgcn_s_setprio(0);
        __builtin_amdgcn_s_barrier();

        // ===== P3: no reads; stage t+2 B2,B3; wait vmcnt(8) (R8 steady state)
        if (pf) { stage1(t + 2, 6); stage1(t + 2, 7); }
        if (pf) asm volatile("s_waitcnt vmcnt(8)" ::: "memory");
        else    asm volatile("s_waitcnt vmcnt(0)" ::: "memory");
        __builtin_amdgcn_sched_barrier(0);
        __builtin_amdgcn_s_barrier();          // tile t+1's A0,A2,B0-B3 ready
        __builtin_amdgcn_s_setprio(1);
#pragma unroll
        for (int ks = 0; ks < 2; ++ks)
#pragma unroll
            for (int ii = 0; ii < 4; ++ii)
#pragma unroll
                for (int j = 0; j < 2; ++j)
                    acc[4 + ii][j] = __builtin_amdgcn_mfma_f32_16x16x32_bf16(
                        av[ii][ks], b01[j][ks], acc[4 + ii][j], 0, 0, 0);
        __builtin_amdgcn_s_setprio(0);
        __builtin_amdgcn_s_barrier();
    }

    // --- epilogue: C write
    const int row0 = c4r * 4;
#pragma unroll
    for (int i = 0; i < 8; ++i) {
#pragma unroll
        for (int j = 0; j < 4; ++j) {
            const int col = bn + wn * 64 + j * 16 + (lane & 15);
#pragma unroll
            for (int r = 0; r < 4; ++r) {
                const size_t row = (size_t)bm + wm * 128 + i * 16 + row0 + r;
                if constexpr (BF16OUT)
                    ((unsigned short*)Cout)[row * N + col] = f2bf(acc[i][j][r]);
                else
                    ((float*)Cout)[row * N + col] = acc[i][j][r];
            }
        }
    }

    if constexpr (FUSE_SUMS) {
        // Wave (wm) covers t-chunks of 32 rows: (trow>>5)+wm*4+ig2, ig2 in 0..3
        const int b = bm >> 13;
        const int trow = bm & 8191;
#pragma unroll
        for (int ig2 = 0; ig2 < 4; ++ig2) {
            const int chunk = (trow >> 5) + wm * 4 + ig2;
            const int t0 = trow + wm * 128 + ig2 * 32 + c4r * 4;
#pragma unroll
            for (int j = 0; j < 4; ++j) {
                const int d = bn + wn * 64 + j * 16 + (lane & 15);
                const float f = freqs[d];
                float ss, cc2;
                sincosf((float)t0 * f, &ss, &cc2);
                float s1, c1;
                sincosf(f, &s1, &c1);
                // e13 = e1^13 via squarings (rows step +1 within r, +13 across frags)
                float c2 = c1 * c1 - s1 * s1, s2 = 2.f * c1 * s1;
                float c4 = c2 * c2 - s2 * s2, s4 = 2.f * c2 * s2;
                float c8 = c4 * c4 - s4 * s4, s8 = 2.f * c4 * s4;
                float c12 = c8 * c4 - s8 * s4, s12 = s8 * c4 + c8 * s4;
                float c13 = c12 * c1 - s12 * s1, s13 = s12 * c1 + c12 * s1;
                float ar = 0.f, ai = 0.f;
                float cr = cc2, sr2 = ss;
#pragma unroll
                for (int f2 = 0; f2 < 2; ++f2) {
                    const int i = ig2 * 2 + f2;
#pragma unroll
                    for (int r = 0; r < 4; ++r) {
                        const float w = acc[i][j][r];
                        ar = fmaf(w, cr, ar); ai = fmaf(w, sr2, ai);
                        const float ec = (r < 3) ? c1 : c13;
                        const float es = (r < 3) ? s1 : s13;
                        const float nc = cr * ec - sr2 * es;
                        const float ns = sr2 * ec + cr * es;
                        cr = nc; sr2 = ns;
                    }
                }
                ar += __shfl_xor(ar, 16); ai += __shfl_xor(ai, 16);
                ar += __shfl_xor(ar, 32); ai += __shfl_xor(ai, 32);
                if (c4r == 0)
                    *(float2*)(csum + (((size_t)b * NCHUNK_ + chunk) * D_ + d) * 2) =
                        make_float2(ar, ai);
            }
        }
    }
}

// One cooperative kernel: cast -> gemm1 -> pass2 -> pass3 -> gemm2.
// Grid MUST be 256 blocks x 512 threads (1 block/CU, exactly co-resident).
__global__ __launch_bounds__(512, 2) void holo_fused(
    const float* x, const float* Wv, const float* Wo, const float* freqs,
    unsigned short* xb,    // also 'ret' after pass3 (x_bf dead post-gemm1)
    unsigned short* wvb, unsigned short* wob,
    float* csum,
    unsigned short* vbf,   // aliases out's first half (dead before gemm2)
    float* out) {
    __shared__ short lds[65536];
    const int tid = threadIdx.x;
    cg::grid_group grid = cg::this_grid();

    // ===== Phase 1: casts (grid-stride, 131072 threads x 18 units)
    {
        const int nx = BT_ * D_ / 8;
        const int nw = D_ * D_ / 8;
        const int ntot = nx + 2 * nw;
        for (int i = blockIdx.x * 512 + tid; i < ntot; i += 256 * 512) {
            const float4* src;
            unsigned short* dst;
            int j;
            if (i < nx)           { src = (const float4*)x;  dst = xb;  j = i; }
            else if (i < nx + nw) { src = (const float4*)Wv; dst = wvb; j = i - nx; }
            else                  { src = (const float4*)Wo; dst = wob; j = i - nx - nw; }
            float4 a = src[j * 2];
            float4 b = src[j * 2 + 1];
            ushort8 o;
            o[0] = f2bf(a.x); o[1] = f2bf(a.y); o[2] = f2bf(a.z); o[3] = f2bf(a.w);
            o[4] = f2bf(b.x); o[5] = f2bf(b.y); o[6] = f2bf(b.z); o[7] = f2bf(b.w);
            *(ushort8*)&dst[(size_t)j * 8] = o;
        }
    }
    grid.sync();

    // ===== Phase 2: v = x @ Wv^T (bf16 out) + fused per-chunk rotor sums
    gemm_body<true, true>((const short*)xb, (const short*)wvb, (void*)vbf,
                          freqs, csum, BT_, D_, D_, lds);
    grid.sync();

    // ===== Phase 3: exclusive prefix of chunk sums (wave per (b,d))
    {
        const int wid = (blockIdx.x << 3) + (tid >> 6);  // 0 .. 2047
        const int lane = tid & 63;
        const int b = wid / D_;
        const int d = wid % D_;
        float2* cs = (float2*)csum;
        const size_t base = (size_t)b * NCHUNK_ * D_ + d;
        float2 s[4];
#pragma unroll
        for (int k = 0; k < 4; ++k)
            s[k] = cs[base + (size_t)(lane * 4 + k) * D_];
        float lr = s[0].x + s[1].x + s[2].x + s[3].x;
        float li = s[0].y + s[1].y + s[2].y + s[3].y;
        float ir = lr, ii = li;
#pragma unroll
        for (int off = 1; off < 64; off <<= 1) {
            float tr = __shfl_up(ir, off);
            float ti = __shfl_up(ii, off);
            if (lane >= off) { ir += tr; ii += ti; }
        }
        float er = ir - lr, ei = ii - li;
#pragma unroll
        for (int k = 0; k < 4; ++k) {
            const float rr = s[k].x, rim = s[k].y;
            cs[base + (size_t)(lane * 4 + k) * D_] = make_float2(er, ei);
            er += rr; ei += rim;
        }
    }
    grid.sync();

    // ===== Phase 4: replay chunk -> ret (in xb region); 4 d's/thread
    {
        const int unit = blockIdx.x * 2 + (tid >> 8);   // 0 .. 511
        const int b = unit >> 8;                        // NCHUNK_ = 256
        const int chunk = unit & (NCHUNK_ - 1);
        const int d0 = (tid & 255) * 4;
        unsigned short* ret = xb;

        float fr[4], s[4], c[4], sf[4], cf[4], ar[4], ai[4];
        {
            float4 f4 = *(const float4*)(freqs + d0);
            fr[0] = f4.x; fr[1] = f4.y; fr[2] = f4.z; fr[3] = f4.w;
        }
        const float t0f = (float)(chunk * CS_);
#pragma unroll
        for (int k = 0; k < 4; ++k) {
            sincosf(t0f * fr[k], &s[k], &c[k]);
            sincosf(fr[k], &sf[k], &cf[k]);
        }
        {
            const size_t cb = (((size_t)b * NCHUNK_ + chunk) * D_ + d0) * 2;
            const float4 o0 = *(const float4*)(csum + cb);
            const float4 o1 = *(const float4*)(csum + cb + 4);
            ar[0] = o0.x; ai[0] = o0.y; ar[1] = o0.z; ai[1] = o0.w;
            ar[2] = o1.x; ai[2] = o1.y; ar[3] = o1.z; ai[3] = o1.w;
        }
        const uint2* vp = (const uint2*)(vbf + ((size_t)b * T_ + chunk * CS_) * D_ + d0);
        uint2* rp = (uint2*)(ret + ((size_t)b * T_ + chunk * CS_) * D_ + d0);
        for (int tb = 0; tb < CS_; tb += 8) {
            uint2 w[8];
#pragma unroll
            for (int u = 0; u < 8; ++u) w[u] = vp[(size_t)(tb + u) * (D_ / 4)];
#pragma unroll
            for (int u = 0; u < 8; ++u) {
                float wv[4], o[4];
                wv[0] = bf2f((unsigned short)w[u].x);
                wv[1] = bf2f((unsigned short)(w[u].x >> 16));
                wv[2] = bf2f((unsigned short)w[u].y);
                wv[3] = bf2f((unsigned short)(w[u].y >> 16));
#pragma unroll
                for (int k = 0; k < 4; ++k) {
                    ar[k] = fmaf(wv[k], c[k], ar[k]);
                    ai[k] = fmaf(wv[k], s[k], ai[k]);
                    o[k] = ar[k] * c[k] + ai[k] * s[k];   // Re(mt * (cos - i sin))
                    float nc = c[k] * cf[k] - s[k] * sf[k];
                    float ns = s[k] * cf[k] + c[k] * sf[k];
                    c[k] = nc; s[k] = ns;
                }
                uint2 ow;
                ow.x = (unsigned int)f2bf(o[0]) | ((unsigned int)f2bf(o[1]) << 16);
                ow.y = (unsigned int)f2bf(o[2]) | ((unsigned int)f2bf(o[3]) << 16);
                rp[(size_t)(tb + u) * (D_ / 4)] = ow;
            }
        }
    }
    grid.sync();

    // ===== Phase 5: out = retrieved @ Wo^T (fp32 out)
    gemm_body<false, false>((const short*)xb, (const short*)wob, (void*)out,
                            nullptr, nullptr, BT_, D_, D_, lds);
}

extern "C" void kernel_launch(void* const* d_in, const int* in_sizes, int n_in,
                              void* d_out, int out_size, void* d_ws, size_t ws_size,
                              hipStream_t stream) {
    const float* x     = (const float*)d_in[0];
    // d_in[1] = Wk (dead in reference)
    const float* Wv    = (const float*)d_in[2];
    const float* Wo    = (const float*)d_in[3];
    const float* freqs = (const float*)d_in[4];
    float* out = (float*)d_out;

    char* ws = (char*)d_ws;
    unsigned short* x_bf  = (unsigned short*)ws;                 // 33,554,432 B (also ret)
    unsigned short* Wv_bf = (unsigned short*)(ws + 33554432);    //  2,097,152 B
    unsigned short* Wo_bf = (unsigned short*)(ws + 35651584);    //  2,097,152 B
    float*          csum  = (float*)(ws + 37748736);             //  4,194,304 B
    unsigned short* v_bf  = (unsigned short*)d_out;              // d_out first half

    void* args[] = {(void*)&x, (void*)&Wv, (void*)&Wo, (void*)&freqs,
                    (void*)&x_bf, (void*)&Wv_bf, (void*)&Wo_bf,
                    (void*)&csum, (void*)&v_bf, (void*)&out};
    hipLaunchCooperativeKernel((const void*)holo_fused, dim3(256), dim3(512),
                               args, 0, stream);
}

// Round 17
// 231.394 us; speedup vs baseline: 1.5621x; 1.5621x over previous
//
#include <hip/hip_runtime.h>
#include <hip/hip_bf16.h>

// HoloAttention: out = (Re(cumsum_t(x@Wv^T * e^{i t f}) * e^{-i t f})) @ Wo^T
// (k-projection in reference is dead code — skipped.)
//
// R23 = revert to R17 verbatim (best measured: 233.6us). R22's cooperative
// fusion POST-MORTEM: single fused dispatch = 261us > 153us sum-of-kernels
// (grid.sync + memory phases pinned at 8 waves/CU by 128KB-LDS co-residency);
// AND dur_us still exceeded kernel time by ~100us -> the ~80us tail residual
// is FIXED per-execution harness overhead (reset/sync), not launch gaps.
// Closed accounting: 2 x ~58us gemms (shape-pinned ~600TF plateau, 6
// structural variants all 54-62us drift band) + ~30us BW-bound small
// kernels + ~80us fixed overhead = ~233us.
// Kernel chain: cast_all -> gemm1(+sums) -> pass2 -> pass3 -> gemm2.

#define B_  2
#define T_  8192
#define D_  1024
#define BT_ 16384
#define CS_ 32
#define NCHUNK_ 256

typedef __attribute__((ext_vector_type(4))) float f32x4;
typedef __attribute__((ext_vector_type(8))) short bf16x8;
typedef __attribute__((ext_vector_type(8))) unsigned short ushort8;

static __device__ inline unsigned short f2bf(float f) {
    union { float f; unsigned int u; } a;
    a.f = f;
    unsigned int u = a.u;
    return (unsigned short)((u + 0x7FFFu + ((u >> 16) & 1u)) >> 16);  // RNE
}
static __device__ inline float bf2f(unsigned short h) {
    union { unsigned int u; float f; } a;
    a.u = ((unsigned int)h) << 16;
    return a.f;
}

// One fused cast, 8 elems/thread: x | Wv | Wo (fp32 -> bf16)
__global__ __launch_bounds__(256) void cast_all(const float* __restrict__ x,
                                                const float* __restrict__ Wv,
                                                const float* __restrict__ Wo,
                                                unsigned short* __restrict__ xb,
                                                unsigned short* __restrict__ wvb,
                                                unsigned short* __restrict__ wob) {
    const int nx = BT_ * D_ / 8;   // ushort8 units
    const int nw = D_ * D_ / 8;
    int i = blockIdx.x * 256 + threadIdx.x;
    const float4* src;
    unsigned short* dst;
    int j;
    if (i < nx)            { src = (const float4*)x;  dst = xb;  j = i; }
    else if (i < nx + nw)  { src = (const float4*)Wv; dst = wvb; j = i - nx; }
    else                   { src = (const float4*)Wo; dst = wob; j = i - nx - nw; }
    float4 a = src[j * 2];
    float4 b = src[j * 2 + 1];
    ushort8 o;
    o[0] = f2bf(a.x); o[1] = f2bf(a.y); o[2] = f2bf(a.z); o[3] = f2bf(a.w);
    o[4] = f2bf(b.x); o[5] = f2bf(b.y); o[6] = f2bf(b.z); o[7] = f2bf(b.w);
    *(ushort8*)&dst[(size_t)j * 8] = o;
}

// C[M,N] = A[M,K] (bf16 row-major) @ Bm[N,K]^T (bf16 row-major).
// 256x256 tile, BK=64, 512 threads = 8 waves (wm = wave>>2 owns 128 rows;
// wn = wave&3 owns 64 cols). 16x16x32 MFMA, acc[8][4] f32x4 per thread.
// LDS: 2 slots x (A 256x64 + B 256x64) bf16 = 131072 B; granule = 64 rows
// (4096 shorts), one block-wide global_load_lds per granule.
// Stage map: P0: t+1 A1,A3 | P1: t+2 A0,A2 | P2: t+2 B0,B1 | P3: t+2 B2,B3.
// Steady-state wait: P3 vmcnt(8) ONLY (R8 structure — frozen).
// Known-accepted: A1,A3(t) read at t P2 one phase before their drain;
// 6 phases (>2000cy) of slack vs ~900cy HBM latency.
template <bool BF16OUT, bool FUSE_SUMS>
__global__ __launch_bounds__(512, 2) void gemm_bt(const short* __restrict__ A,
                                                  const short* __restrict__ Bm,
                                                  void* __restrict__ Cout,
                                                  const float* __restrict__ freqs,
                                                  float* __restrict__ csum,
                                                  int M, int N, int K) {
    __shared__ short lds[65536];  // 2 x 32768 shorts (A at +0, B at +16384)
    const int tid = threadIdx.x;
    const int lane = tid & 63;
    const int wave = tid >> 6;
    const int wm = wave >> 2, wn = wave & 3;

    const int nb = N >> 8;               // N-blocks (4)
    const int id = blockIdx.x;
    const int xcd = id & 7;
    const int slot = id >> 3;
    const int bn = (slot % nb) * 256;
    const int bm = (xcd * ((M >> 8) >> 3) + slot / nb) * 256;

    // --- staging: granule g = 64 rows of A (g=0..3) or B (g=4..7).
    const int srow = lane >> 3;
    const int sg = lane & 7;
    const size_t cstep = (size_t)64 * K;
    const short* gA = A + (size_t)(bm + wave * 8 + srow) * K + ((sg ^ srow) * 8);
    const short* gB = Bm + (size_t)(bn + wave * 8 + srow) * K + ((sg ^ srow) * 8);

    auto stage1 = [&](int kt, int g) {
        const int c = g & 3;
        const short* src = ((g & 4) ? gB : gA) + c * cstep + kt * 64;
        short* dst = &lds[(kt & 1) * 32768 + ((g & 4) ? 16384 : 0) + c * 4096 + wave * 512];
        __builtin_amdgcn_global_load_lds(
            (const __attribute__((address_space(1))) void*)src,
            (__attribute__((address_space(3))) void*)dst, 16, 0, 0);
    };

    // --- fragment read bases (shorts). m&7 == lane&7 for every fragment row.
    const int l15 = lane & 15;
    const int c4r = lane >> 4;
    const int swz0 = ((c4r) ^ (lane & 7)) * 8;
    const int swz1 = ((4 + c4r) ^ (lane & 7)) * 8;
    const int abase = (wm * 128 + l15) * 64;
    const int bbase = 16384 + (wn * 64 + l15) * 64;

    f32x4 acc[8][4] = {};

    // --- prologue: tile0 fully (8), tile1 all but A1,A3 (6).
    stage1(0, 0); stage1(0, 1); stage1(0, 2); stage1(0, 3);
    stage1(0, 4); stage1(0, 5); stage1(0, 6); stage1(0, 7);
    stage1(1, 0); stage1(1, 2);
    stage1(1, 4); stage1(1, 5); stage1(1, 6); stage1(1, 7);
    asm volatile("s_waitcnt vmcnt(6)" ::: "memory");   // ALL of tile0 landed (one-time)
    __builtin_amdgcn_sched_barrier(0);
    __builtin_amdgcn_s_barrier();

    const int NT = K >> 6;  // 16
#pragma unroll 1
    for (int t = 0; t < NT; ++t) {
        const int sb = (t & 1) * 32768;
        const bool pf = (t + 2 < NT);
        bf16x8 av[4][2], b01[2][2], b23[2][2];

        // ===== P0: quad (rows 0-63, cols 0-31): reads A frags 0-3 (8) + b01 (4);
        //       stage t+1 A1,A3
#pragma unroll
        for (int ii = 0; ii < 4; ++ii) {
            av[ii][0] = *(const bf16x8*)&lds[sb + abase + ii * 1024 + swz0];
            av[ii][1] = *(const bf16x8*)&lds[sb + abase + ii * 1024 + swz1];
        }
#pragma unroll
        for (int j = 0; j < 2; ++j) {
            b01[j][0] = *(const bf16x8*)&lds[sb + bbase + j * 1024 + swz0];
            b01[j][1] = *(const bf16x8*)&lds[sb + bbase + j * 1024 + swz1];
        }
        if (t + 1 < NT) { stage1(t + 1, 1); stage1(t + 1, 3); }
        __builtin_amdgcn_s_barrier();
        asm volatile("s_waitcnt lgkmcnt(0)" ::: "memory");
        __builtin_amdgcn_sched_barrier(0);
        __builtin_amdgcn_s_setprio(1);
#pragma unroll
        for (int ks = 0; ks < 2; ++ks)
#pragma unroll
            for (int ii = 0; ii < 4; ++ii)
#pragma unroll
                for (int j = 0; j < 2; ++j)
                    acc[ii][j] = __builtin_amdgcn_mfma_f32_16x16x32_bf16(
                        av[ii][ks], b01[j][ks], acc[ii][j], 0, 0, 0);
        __builtin_amdgcn_s_setprio(0);
        __builtin_amdgcn_s_barrier();

        // ===== P1: quad (rows 0-63, cols 32-63): reads b23 (4); stage t+2 A0,A2
#pragma unroll
        for (int j = 0; j < 2; ++j) {
            b23[j][0] = *(const bf16x8*)&lds[sb + bbase + (2 + j) * 1024 + swz0];
            b23[j][1] = *(const bf16x8*)&lds[sb + bbase + (2 + j) * 1024 + swz1];
        }
        if (pf) { stage1(t + 2, 0); stage1(t + 2, 2); }
        __builtin_amdgcn_s_barrier();
        asm volatile("s_waitcnt lgkmcnt(0)" ::: "memory");
        __builtin_amdgcn_sched_barrier(0);
        __builtin_amdgcn_s_setprio(1);
#pragma unroll
        for (int ks = 0; ks < 2; ++ks)
#pragma unroll
            for (int ii = 0; ii < 4; ++ii)
#pragma unroll
                for (int j = 0; j < 2; ++j)
                    acc[ii][2 + j] = __builtin_amdgcn_mfma_f32_16x16x32_bf16(
                        av[ii][ks], b23[j][ks], acc[ii][2 + j], 0, 0, 0);
        __builtin_amdgcn_s_setprio(0);
        __builtin_amdgcn_s_barrier();

        // ===== P2: quad (rows 64-127, cols 32-63): reads A frags 4-7 (8);
        //       stage t+2 B0,B1. A1,A3(t) staged at t-1 P0 (6 phases ago) —
        //       read WITHOUT an explicit wait (R8 structure — frozen).
#pragma unroll
        for (int ii = 0; ii < 4; ++ii) {
            av[ii][0] = *(const bf16x8*)&lds[sb + abase + (4 + ii) * 1024 + swz0];
            av[ii][1] = *(const bf16x8*)&lds[sb + abase + (4 + ii) * 1024 + swz1];
        }
        if (pf) { stage1(t + 2, 4); stage1(t + 2, 5); }
        __builtin_amdgcn_s_barrier();
        asm volatile("s_waitcnt lgkmcnt(0)" ::: "memory");
        __builtin_amdgcn_sched_barrier(0);
        __builtin_amdgcn_s_setprio(1);
#pragma unroll
        for (int ks = 0; ks < 2; ++ks)
#pragma unroll
            for (int ii = 0; ii < 4; ++ii)
#pragma unroll
                for (int j = 0; j < 2; ++j)
                    acc[4 + ii][2 + j] = __builtin_amdgcn_mfma_f32_16x16x32_bf16(
                        av[ii][ks], b23[j][ks], acc[4 + ii][2 + j], 0, 0, 0);
        __builtin_amdgcn_s_setprio(0);
        __builtin_amdgcn_s_barrier();

        // ===== P3: quad (rows 64-127, cols 0-31): no reads; stage t+2 B2,B3;
        //       wait vmcnt(8): drains A1,A3(t) + A0,A2,B0-B3(t+1); keeps
        //       A1,A3(t+1) + t+2's 6 in flight (R8's exact steady state).
        if (pf) { stage1(t + 2, 6); stage1(t + 2, 7); }
        if (pf) asm volatile("s_waitcnt vmcnt(8)" ::: "memory");
        else    asm volatile("s_waitcnt vmcnt(0)" ::: "memory");
        __builtin_amdgcn_sched_barrier(0);
        __builtin_amdgcn_s_barrier();          // tile t+1's A0,A2,B0-B3 ready
        __builtin_amdgcn_s_setprio(1);
#pragma unroll
        for (int ks = 0; ks < 2; ++ks)
#pragma unroll
            for (int ii = 0; ii < 4; ++ii)
#pragma unroll
                for (int j = 0; j < 2; ++j)
                    acc[4 + ii][j] = __builtin_amdgcn_mfma_f32_16x16x32_bf16(
                        av[ii][ks], b01[j][ks], acc[4 + ii][j], 0, 0, 0);
        __builtin_amdgcn_s_setprio(0);
        __builtin_amdgcn_s_barrier();
    }

    // --- epilogue: C write
    const int row0 = c4r * 4;
#pragma unroll
    for (int i = 0; i < 8; ++i) {
#pragma unroll
        for (int j = 0; j < 4; ++j) {
            const int col = bn + wn * 64 + j * 16 + (lane & 15);
#pragma unroll
            for (int r = 0; r < 4; ++r) {
                const size_t row = (size_t)bm + wm * 128 + i * 16 + row0 + r;
                if constexpr (BF16OUT)
                    ((unsigned short*)Cout)[row * N + col] = f2bf(acc[i][j][r]);
                else
                    ((float*)Cout)[row * N + col] = acc[i][j][r];
            }
        }
    }

    if constexpr (FUSE_SUMS) {
        // Wave (wm) covers t-chunks of 32 rows: (trow>>5)+wm*4+ig2, ig2 in 0..3
        // (chunk = acc frags {2ig2, 2ig2+1}).
        const int b = bm >> 13;
        const int trow = bm & 8191;
#pragma unroll
        for (int ig2 = 0; ig2 < 4; ++ig2) {
            const int chunk = (trow >> 5) + wm * 4 + ig2;
            const int t0 = trow + wm * 128 + ig2 * 32 + c4r * 4;
#pragma unroll
            for (int j = 0; j < 4; ++j) {
                const int d = bn + wn * 64 + j * 16 + (lane & 15);
                const float f = freqs[d];
                float ss, cc2;
                sincosf((float)t0 * f, &ss, &cc2);
                float s1, c1;
                sincosf(f, &s1, &c1);
                // e13 = e1^13 via squarings (rows step +1 within r, +13 across frags)
                float c2 = c1 * c1 - s1 * s1, s2 = 2.f * c1 * s1;
                float c4 = c2 * c2 - s2 * s2, s4 = 2.f * c2 * s2;
                float c8 = c4 * c4 - s4 * s4, s8 = 2.f * c4 * s4;
                float c12 = c8 * c4 - s8 * s4, s12 = s8 * c4 + c8 * s4;
                float c13 = c12 * c1 - s12 * s1, s13 = s12 * c1 + c12 * s1;
                float ar = 0.f, ai = 0.f;
                float cr = cc2, sr2 = ss;
#pragma unroll
                for (int f2 = 0; f2 < 2; ++f2) {
                    const int i = ig2 * 2 + f2;
#pragma unroll
                    for (int r = 0; r < 4; ++r) {
                        const float w = acc[i][j][r];
                        ar = fmaf(w, cr, ar); ai = fmaf(w, sr2, ai);
                        const float ec = (r < 3) ? c1 : c13;
                        const float es = (r < 3) ? s1 : s13;
                        const float nc = cr * ec - sr2 * es;
                        const float ns = sr2 * ec + cr * es;
                        cr = nc; sr2 = ns;
                    }
                }
                ar += __shfl_xor(ar, 16); ai += __shfl_xor(ai, 16);
                ar += __shfl_xor(ar, 32); ai += __shfl_xor(ai, 32);
                if (c4r == 0)
                    *(float2*)(csum + (((size_t)b * NCHUNK_ + chunk) * D_ + d) * 2) =
                        make_float2(ar, ai);
            }
        }
    }
}

// Pass 2: exclusive prefix of chunk sums per (b,d) — wave-parallel scan.
// One 64-lane wave per (b,d): lane l owns chunks [4l, 4l+4); 6-step shfl_up
// inclusive scan of lane totals; exclusive writeback. 2048 waves total.
__global__ __launch_bounds__(512) void scan_pass2(float* __restrict__ csum) {
    const int wid = (blockIdx.x * 512 + threadIdx.x) >> 6;  // 0 .. B*D-1
    const int lane = threadIdx.x & 63;
    const int b = wid / D_;
    const int d = wid % D_;
    float2* cs = (float2*)csum;
    const size_t base = (size_t)b * NCHUNK_ * D_ + d;

    float2 s[4];
#pragma unroll
    for (int k = 0; k < 4; ++k)
        s[k] = cs[base + (size_t)(lane * 4 + k) * D_];
    float lr = s[0].x + s[1].x + s[2].x + s[3].x;
    float li = s[0].y + s[1].y + s[2].y + s[3].y;

    float ir = lr, ii = li;   // inclusive scan of lane totals
#pragma unroll
    for (int off = 1; off < 64; off <<= 1) {
        float tr = __shfl_up(ir, off);
        float ti = __shfl_up(ii, off);
        if (lane >= off) { ir += tr; ii += ti; }
    }
    float er = ir - lr, ei = ii - li;  // exclusive prefix at lane start
#pragma unroll
    for (int k = 0; k < 4; ++k) {
        const float rr = s[k].x, rim = s[k].y;
        cs[base + (size_t)(lane * 4 + k) * D_] = make_float2(er, ei);
        er += rr; ei += rim;
    }
}

// Pass 3: replay chunk; retrieved = Re(mt * conj(rotor)) -> bf16; 2 d's/thread,
// CS=32, 8-row load batches, grid (NCHUNK, D/512, B) = 1024 blocks.
__global__ __launch_bounds__(256) void scan_pass3(const unsigned short* __restrict__ v,
                                                  const float* __restrict__ freqs,
                                                  const float* __restrict__ csum,
                                                  unsigned short* __restrict__ ret) {
    const int chunk = blockIdx.x;
    const int d0 = blockIdx.y * 512 + threadIdx.x * 2;
    const int b = blockIdx.z;

    float fr[2], s[2], c[2], sf[2], cf[2], ar[2], ai[2];
    {
        float2 f2 = *(const float2*)(freqs + d0);
        fr[0] = f2.x; fr[1] = f2.y;
    }
    const float t0f = (float)(chunk * CS_);
#pragma unroll
    for (int k = 0; k < 2; ++k) {
        sincosf(t0f * fr[k], &s[k], &c[k]);
        sincosf(fr[k], &sf[k], &cf[k]);
    }
    {
        const float4 o = *(const float4*)(csum + (((size_t)b * NCHUNK_ + chunk) * D_ + d0) * 2);
        ar[0] = o.x; ai[0] = o.y; ar[1] = o.z; ai[1] = o.w;
    }
    const unsigned int* vp = (const unsigned int*)(v + ((size_t)b * T_ + chunk * CS_) * D_ + d0);
    unsigned int* rp = (unsigned int*)(ret + ((size_t)b * T_ + chunk * CS_) * D_ + d0);
    for (int tb = 0; tb < CS_; tb += 8) {
        unsigned int w[8];
#pragma unroll
        for (int u = 0; u < 8; ++u) w[u] = vp[(size_t)(tb + u) * (D_ / 2)];
#pragma unroll
        for (int u = 0; u < 8; ++u) {
            float wv[2], o[2];
            wv[0] = bf2f((unsigned short)w[u]);
            wv[1] = bf2f((unsigned short)(w[u] >> 16));
#pragma unroll
            for (int k = 0; k < 2; ++k) {
                ar[k] = fmaf(wv[k], c[k], ar[k]);
                ai[k] = fmaf(wv[k], s[k], ai[k]);
                o[k] = ar[k] * c[k] + ai[k] * s[k];   // Re(mt * (cos - i sin))
                float nc = c[k] * cf[k] - s[k] * sf[k];
                float ns = s[k] * cf[k] + c[k] * sf[k];
                c[k] = nc; s[k] = ns;
            }
            rp[(size_t)(tb + u) * (D_ / 2)] =
                (unsigned int)f2bf(o[0]) | ((unsigned int)f2bf(o[1]) << 16);
        }
    }
}

extern "C" void kernel_launch(void* const* d_in, const int* in_sizes, int n_in,
                              void* d_out, int out_size, void* d_ws, size_t ws_size,
                              hipStream_t stream) {
    const float* x     = (const float*)d_in[0];
    // d_in[1] = Wk (dead in reference)
    const float* Wv    = (const float*)d_in[2];
    const float* Wo    = (const float*)d_in[3];
    const float* freqs = (const float*)d_in[4];
    float* out = (float*)d_out;

    char* ws = (char*)d_ws;
    unsigned short* x_bf  = (unsigned short*)ws;                 // 33,554,432 B
    unsigned short* Wv_bf = (unsigned short*)(ws + 33554432);    //  2,097,152 B
    unsigned short* Wo_bf = (unsigned short*)(ws + 35651584);    //  2,097,152 B
    float*          csum  = (float*)(ws + 37748736);             //  4,194,304 B (B*256*D*2*4)
    // ret reuses x_bf's region: x_bf is dead after gemm1 (stream-ordered),
    // pass3 writes ret there, gemm2 reads it. v (bf16) lives in d_out's
    // first half; dead before GEMM2 overwrites d_out.
    unsigned short* ret  = (unsigned short*)ws;
    unsigned short* v_bf = (unsigned short*)d_out;

    // 1. fused casts (x | Wv | Wo), 8 elems/thread
    cast_all<<<(BT_ * D_ / 8 + 2 * D_ * D_ / 8) / 256, 256, 0, stream>>>(
        x, Wv, Wo, x_bf, Wv_bf, Wo_bf);

    // 2. v = x @ Wv^T (bf16 out) + fused per-chunk rotor sums
    gemm_bt<true, true><<<(BT_ / 256) * (D_ / 256), 512, 0, stream>>>(
        (const short*)x_bf, (const short*)Wv_bf, (void*)v_bf, freqs, csum, BT_, D_, D_);

    // 3. exclusive prefix over chunks (wave-parallel), then replay+unbind
    scan_pass2<<<(B_ * D_ * 64) / 512, 512, 0, stream>>>(csum);
    dim3 p3grid(NCHUNK_, D_ / 512, B_);
    scan_pass3<<<p3grid, 256, 0, stream>>>(v_bf, freqs, csum, ret);

    // 4. out = retrieved @ Wo^T (fp32 out)
    gemm_bt<false, false><<<(BT_ / 256) * (D_ / 256), 512, 0, stream>>>(
        (const short*)ret, (const short*)Wo_bf, (void*)out, nullptr, nullptr, BT_, D_, D_);
}